// Round 1
// 211.413 us; speedup vs baseline: 1.0037x; 1.0037x over previous
//
#include <hip/hip_runtime.h>
#include <math.h>

// GRU: B=65536, T=9, I=57, H=2, O=1.
// R3: split each batch element's 6 gate dot-products across TWO waves
// (wave w handles hidden index w: Wih rows {w, 2+w, 4+w}).
// 128-thread blocks / 64 elements -> 2048 waves = 2 waves/SIMD (was 1),
// halving per-wave VALU+DMA and doubling latency hiding. Hidden state is
// exchanged via a parity-double-buffered LDS slot using the existing
// per-timestep barrier. Weight pointers stay wave-uniform -> scalar loads.
// Dual accumulators halve the dependent-FMA chain depth (28 ~= issue rate).

#define T_STEPS 9
#define I_DIM   57
#define ROW_F   513           // T*I floats per batch element
#define TILE_F  (64 * I_DIM)  // 3648 floats per tile buffer
#define NK      29            // DMA instructions per wave (wave1 uses 28)

__device__ __forceinline__ float sigm(float x) {
    return 1.0f / (1.0f + __expf(-x));
}
__device__ __forceinline__ float tanh_fast(float x) {
    x = fminf(fmaxf(x, -15.0f), 15.0f);
    float e = __expf(2.0f * x);
    return (e - 1.0f) / (e + 1.0f);
}

__global__ __launch_bounds__(128, 2) void gru_kernel(
    const float* __restrict__ x,    // [B, T, I]
    const float* __restrict__ Wih,  // [6, 57]
    const float* __restrict__ Whh,  // [6, 2]
    const float* __restrict__ bih,  // [6]
    const float* __restrict__ bhh,  // [6]
    const float* __restrict__ fcw,  // [1, 2]
    const float* __restrict__ fcb,  // [1]
    float* __restrict__ out)        // [B, 1]
{
    __shared__ float tile[2][TILE_F];
    __shared__ float hx[2][2][64];  // [parity][w][elem] hidden exchange
    const int lane = threadIdx.x & 63;
    const int w    = __builtin_amdgcn_readfirstlane(threadIdx.x >> 6);
    const int blk  = blockIdx.x;
    const char* xblk = (const char*)(x + (size_t)blk * 64 * ROW_F);

    // Per-lane byte offsets for this wave's share of the staging loads:
    // flat f = (w*64 + lane) + 128*k over the block's 64*57-float tile,
    // elem = f/57, col = f%57, address = elem*2052 + col*4 (incremental,
    // no integer division). Wave w stages LDS floats [64*(2k+w), +64).
    int offB[NK];
    {
        const int f0 = w * 64 + lane;
        int row = (f0 >= 2 * I_DIM) ? 2 : ((f0 >= I_DIM) ? 1 : 0);
        int col = f0 - row * I_DIM;
#pragma unroll
        for (int k = 0; k < NK; ++k) {
            offB[k] = row * (ROW_F * 4) + col * 4;
            row += 2; col += 14;                  // f += 128 = 2*57 + 14
            if (col >= I_DIM) { row += 1; col -= I_DIM; }
        }
    }

    // Async-stage timestep t's 64x57 tile into tile[buf]; each wave stages
    // its interleaved half. LDS dest per instruction is wave-uniform base
    // (+ HW lane*4), matching f = 64*(2k+w) + lane exactly.
    auto issue_tile = [&](int t, int buf) {
        const char* base = xblk + t * (I_DIM * 4);
#pragma unroll
        for (int k = 0; k < NK; ++k) {
            if (2 * k + w < I_DIM) {
                __builtin_amdgcn_global_load_lds(
                    (const __attribute__((address_space(1))) void*)(base + offB[k]),
                    (__attribute__((address_space(3))) void*)(&tile[buf][64 * (2 * k + w)]),
                    4, 0, 0);
            }
        }
    };

    issue_tile(0, 0);
    hx[0][w][lane] = 0.0f;  // h(t=0) = 0 for both hidden indices

    // This wave's gate rows (r=row w, z=row 2+w, n=row 4+w): wave-uniform.
    const float* WR = Wih + (0 + w) * I_DIM;
    const float* WZ = Wih + (2 + w) * I_DIM;
    const float* WN = Wih + (4 + w) * I_DIM;
    const float bR = bih[0 + w], bZ = bih[2 + w], bN = bih[4 + w];
    const float cR = bhh[0 + w], cZ = bhh[2 + w], cN = bhh[4 + w];
    const float wr0 = Whh[(0 + w) * 2], wr1 = Whh[(0 + w) * 2 + 1];
    const float wz0 = Whh[(2 + w) * 2], wz1 = Whh[(2 + w) * 2 + 1];
    const float wn0 = Whh[(4 + w) * 2], wn1 = Whh[(4 + w) * 2 + 1];

    float hm = 0.0f;  // h[w] ("mine"); partner's h comes via LDS

#pragma unroll 1
    for (int t = 0; t < T_STEPS; ++t) {
        __syncthreads();                      // tile[t&1] + hx[t&1] ready
        const float ho = hx[t & 1][1 - w][lane];         // partner hidden
        if (t + 1 < T_STEPS) issue_tile(t + 1, (t + 1) & 1);   // prefetch

        // Cache this lane's x-row (stride 57 floats -> 2-way bank alias
        // only = free).
        const float* rowp = &tile[t & 1][lane * I_DIM];
        float xr[I_DIM];
#pragma unroll
        for (int i = 0; i < I_DIM; ++i) xr[i] = rowp[i];

        // Three 57-dots, dual accumulators (chain depth 28 ~ issue rate).
        float r0 = bR, r1 = 0.0f;
#pragma unroll
        for (int i = 0; i < I_DIM - 1; i += 2) {
            r0 = fmaf(xr[i],     WR[i],     r0);
            r1 = fmaf(xr[i + 1], WR[i + 1], r1);
        }
        r0 = fmaf(xr[I_DIM - 1], WR[I_DIM - 1], r0);
        const float aR = r0 + r1;

        float z0 = bZ, z1 = 0.0f;
#pragma unroll
        for (int i = 0; i < I_DIM - 1; i += 2) {
            z0 = fmaf(xr[i],     WZ[i],     z0);
            z1 = fmaf(xr[i + 1], WZ[i + 1], z1);
        }
        z0 = fmaf(xr[I_DIM - 1], WZ[I_DIM - 1], z0);
        const float aZ = z0 + z1;

        float n0 = bN, n1 = 0.0f;
#pragma unroll
        for (int i = 0; i < I_DIM - 1; i += 2) {
            n0 = fmaf(xr[i],     WN[i],     n0);
            n1 = fmaf(xr[i + 1], WN[i + 1], n1);
        }
        n0 = fmaf(xr[I_DIM - 1], WN[I_DIM - 1], n0);
        const float aN = n0 + n1;

        // Hidden-side projections need (h0, h1): uniform select by wave.
        const float h0 = w ? ho : hm;
        const float h1 = w ? hm : ho;
        const float gR = cR + wr0 * h0 + wr1 * h1;
        const float gZ = cZ + wz0 * h0 + wz1 * h1;
        const float gN = cN + wn0 * h0 + wn1 * h1;

        const float r = sigm(aR + gR);
        const float z = sigm(aZ + gZ);
        const float n = tanh_fast(aN + r * gN);
        hm = (1.0f - z) * n + z * hm;

        hx[(t + 1) & 1][w][lane] = hm;  // parity-buffered: no WAR race
    }

    __syncthreads();  // final h exchange visible
    if (w == 0) {
        const float h1f = hx[T_STEPS & 1][1][lane];
        out[blk * 64 + lane] = fcw[0] * hm + fcw[1] * h1f + fcb[0];
    }
}

extern "C" void kernel_launch(void* const* d_in, const int* in_sizes, int n_in,
                              void* d_out, int out_size, void* d_ws, size_t ws_size,
                              hipStream_t stream) {
    const float* x   = (const float*)d_in[0];
    const float* Wih = (const float*)d_in[1];
    const float* Whh = (const float*)d_in[2];
    const float* bih = (const float*)d_in[3];
    const float* bhh = (const float*)d_in[4];
    const float* fcw = (const float*)d_in[5];
    const float* fcb = (const float*)d_in[6];
    float* out = (float*)d_out;

    gru_kernel<<<dim3(1024), dim3(128), 0, stream>>>(
        x, Wih, Whh, bih, bhh, fcw, fcb, out);
}